// Round 4
// baseline (641.117 us; speedup 1.0000x reference)
//
#include <hip/hip_runtime.h>
#include <hip/hip_bf16.h>

typedef __attribute__((ext_vector_type(8))) short short8;
typedef __attribute__((ext_vector_type(4))) float f32x4;

__device__ inline f32x4 mfma16(short8 a, short8 b, f32x4 c) {
    return __builtin_amdgcn_mfma_f32_16x16x32_bf16(a, b, c, 0, 0, 0);
}
__device__ inline short f2bf(float x) {
    __hip_bfloat16 h = __float2bfloat16(x);
    return *reinterpret_cast<short*>(&h);
}
__device__ inline float scrub(float v, float s) {
    return (fabsf(v) < 1e30f) ? v : s;  // NaN/inf -> sentinel
}

// ---- dtype detection: flag=1 if x is fp32 (read-as-bf16 looks implausible) --
__global__ void detect_dtype(const unsigned short* __restrict__ x, int* flag) {
    __shared__ int cnt;
    if (threadIdx.x == 0) cnt = 0;
    __syncthreads();
    int c = 0;
    for (int i = threadIdx.x; i < 1024; i += 256) {
        unsigned short u = x[i];
        int e = (u >> 7) & 0xFF;                       // bf16 exponent
        if ((u & 0x7FFF) == 0 || (e >= 110 && e <= 143)) c++;  // |v| in ~[1e-5,1e5] or 0
    }
    atomicAdd(&cnt, c);
    __syncthreads();
    if (threadIdx.x == 0) flag[0] = (cnt < 819) ? 1 : 0;
}

__global__ void conv_bias(const void* __restrict__ in, short* __restrict__ out,
                          int n, const int* __restrict__ flag) {
    int i = blockIdx.x * 256 + threadIdx.x;
    if (i >= n) return;
    out[i] = (*flag) ? f2bf(((const float*)in)[i]) : ((const short*)in)[i];
}

__global__ void fill_sentinel(void* out, int n, const int* __restrict__ flag) {
    int i = blockIdx.x * 256 + threadIdx.x;
    if (i >= n) return;
    if (*flag) ((float*)out)[i] = 3e5f; else ((short*)out)[i] = f2bf(3e5f);
}

// ---- transpose (poly input): in[R][C] -> out[C][R], out bf16 ----
__global__ __launch_bounds__(256) void transpose_poly(const void* __restrict__ in,
                                                      short* __restrict__ out,
                                                      int R, int C,
                                                      const int* __restrict__ flag) {
    __shared__ short tile[32][33];
    const bool f32 = (*flag) != 0;
    int tx = threadIdx.x & 31, ty = threadIdx.x >> 5;
    int r0 = blockIdx.y * 32, c0 = blockIdx.x * 32;
#pragma unroll
    for (int i = 0; i < 4; i++) {
        size_t off = (size_t)(r0 + ty + i * 8) * C + c0 + tx;
        tile[ty + i * 8][tx] = f32 ? f2bf(((const float*)in)[off]) : ((const short*)in)[off];
    }
    __syncthreads();
#pragma unroll
    for (int i = 0; i < 4; i++)
        out[(size_t)(c0 + ty + i * 8) * R + r0 + tx] = tile[tx][ty + i * 8];
}

// ---- GEMM: C[M,N] = A[m_off+.. ,K] @ Bt[N,K]^T + bias ----
// A poly (if a_poly), C poly (if c_poly); Bt/bias always bf16. NaN-scrubbed.
#define LDK 72

__global__ __launch_bounds__(256) void gemm_bt(const void* __restrict__ A,
                                               const short* __restrict__ Bt,
                                               const short* __restrict__ bias,
                                               void* __restrict__ Cv,
                                               int N, int K, int m_off,
                                               const int* __restrict__ flag,
                                               int a_poly, int c_poly, float sent) {
    alignas(16) __shared__ short As[128 * LDK];
    alignas(16) __shared__ short Bs[128 * LDK];
    const bool af32 = a_poly && (*flag);
    const bool cf32 = c_poly && (*flag);
    int tid = threadIdx.x;
    int wave = tid >> 6, lane = tid & 63;
    int lrow = lane & 15, lq = lane >> 4;
    int wm = (wave >> 1) * 64, wn = (wave & 1) * 64;
    int m0 = blockIdx.y * 128, n0 = blockIdx.x * 128;

    f32x4 acc[4][4];
#pragma unroll
    for (int i = 0; i < 4; i++)
#pragma unroll
        for (int j = 0; j < 4; j++) acc[i][j] = (f32x4){0.f, 0.f, 0.f, 0.f};

    int srow = tid >> 3;
    int scol = (tid & 7) * 8;

    for (int kb = 0; kb < K; kb += 64) {
#pragma unroll
        for (int p = 0; p < 4; p++) {
            int row = p * 32 + srow;
            size_t aoff = (size_t)(m_off + m0 + row) * K + kb + scol;
            if (af32) {
                const float* Af = (const float*)A;
                float4 f0 = *(const float4*)&Af[aoff];
                float4 f1 = *(const float4*)&Af[aoff + 4];
                short8 v;
                v[0] = f2bf(f0.x); v[1] = f2bf(f0.y); v[2] = f2bf(f0.z); v[3] = f2bf(f0.w);
                v[4] = f2bf(f1.x); v[5] = f2bf(f1.y); v[6] = f2bf(f1.z); v[7] = f2bf(f1.w);
                *(short8*)&As[row * LDK + scol] = v;
            } else {
                *(short8*)&As[row * LDK + scol] = *(const short8*)&((const short*)A)[aoff];
            }
            *(short8*)&Bs[row * LDK + scol] =
                *(const short8*)&Bt[(size_t)(n0 + row) * K + kb + scol];
        }
        __syncthreads();
#pragma unroll
        for (int ks = 0; ks < 2; ks++) {
            short8 af[4], bf[4];
#pragma unroll
            for (int i = 0; i < 4; i++)
                af[i] = *(short8*)&As[(wm + i * 16 + lrow) * LDK + ks * 32 + lq * 8];
#pragma unroll
            for (int i = 0; i < 4; i++)
                bf[i] = *(short8*)&Bs[(wn + i * 16 + lrow) * LDK + ks * 32 + lq * 8];
#pragma unroll
            for (int i = 0; i < 4; i++)
#pragma unroll
                for (int j = 0; j < 4; j++)
                    acc[i][j] = mfma16(af[i], bf[j], acc[i][j]);
        }
        __syncthreads();
    }

    const __hip_bfloat16* bias16 = (const __hip_bfloat16*)bias;
#pragma unroll
    for (int j = 0; j < 4; j++) {
        int col = n0 + wn + j * 16 + lrow;
        float bv = __bfloat162float(bias16[col]);
#pragma unroll
        for (int i = 0; i < 4; i++) {
            int rbase = m0 + wm + i * 16 + lq * 4;
#pragma unroll
            for (int r = 0; r < 4; r++) {
                float val = scrub(acc[i][j][r] + bv, sent);
                size_t off = (size_t)(rbase + r) * N + col;
                if (cf32) ((float*)Cv)[off] = val; else ((short*)Cv)[off] = f2bf(val);
            }
        }
    }
}

// ---- flash attention (bf16 in/out, internals fp32) ----
#define VP 56

__global__ __launch_bounds__(256) void attn_kernel(const short* __restrict__ QKV,
                                                   short* __restrict__ AO,
                                                   const int* __restrict__ maskp) {
    constexpr int S = 2048, C3 = 3072;
    alignas(16) __shared__ short Vt[64 * VP];
    alignas(16) __shared__ short Pt[4][16 * VP];

    int tid = threadIdx.x;
    int wave = tid >> 6, lane = tid & 63;
    int lrow = lane & 15, lq = lane >> 4;
    int q0 = blockIdx.x * 64;
    int bh = blockIdx.y;
    const bool causal = (*maskp) != 0;
    const short* base = QKV + (size_t)(bh >> 4) * S * C3 + (bh & 15) * 192;

    int qrow = q0 + wave * 16 + lrow;
    short8 qf0 = *(const short8*)(base + (size_t)qrow * C3 + lq * 8);
    short8 qf1 = *(const short8*)(base + (size_t)qrow * C3 + 32 + lq * 8);

    float m_r[4], l_r[4];
    f32x4 acc[4];
#pragma unroll
    for (int r = 0; r < 4; r++) { m_r[r] = -1e38f; l_r[r] = 0.f; }
#pragma unroll
    for (int nt = 0; nt < 4; nt++) acc[nt] = (f32x4){0.f, 0.f, 0.f, 0.f};

    int qi_base = q0 + wave * 16 + lq * 4;
    int nkv = causal ? (q0 + 64) : S;
    int vi = tid & 31;
    int vc = (tid >> 5) * 8;

    for (int kv0 = 0; kv0 < nkv; kv0 += 32) {
        {
            short8 v = *(const short8*)(base + (size_t)(kv0 + vi) * C3 + 128 + vc);
#pragma unroll
            for (int j = 0; j < 8; j++) Vt[(vc + j) * VP + vi] = v[j];
        }
        __syncthreads();

        f32x4 s[2];
#pragma unroll
        for (int sub = 0; sub < 2; sub++) {
            const short* kb = base + (size_t)(kv0 + sub * 16 + lrow) * C3 + 64;
            short8 kf0 = *(const short8*)(kb + lq * 8);
            short8 kf1 = *(const short8*)(kb + 32 + lq * 8);
            f32x4 a = (f32x4){0.f, 0.f, 0.f, 0.f};
            a = mfma16(qf0, kf0, a);
            a = mfma16(qf1, kf1, a);
            s[sub] = a;
        }

#pragma unroll
        for (int sub = 0; sub < 2; sub++) {
            int kvi = kv0 + sub * 16 + lrow;
#pragma unroll
            for (int r = 0; r < 4; r++) {
                float v = s[sub][r] * 0.125f;
                if (causal && kvi > qi_base + r) v = -1e30f;
                s[sub][r] = v;
            }
        }

        float alpha[4];
#pragma unroll
        for (int r = 0; r < 4; r++) {
            float v = fmaxf(s[0][r], s[1][r]);
            v = fmaxf(v, __shfl_xor(v, 1, 64));
            v = fmaxf(v, __shfl_xor(v, 2, 64));
            v = fmaxf(v, __shfl_xor(v, 4, 64));
            v = fmaxf(v, __shfl_xor(v, 8, 64));
            float nm = fmaxf(m_r[r], v);
            alpha[r] = __expf(m_r[r] - nm);
            m_r[r] = nm;
            float p0 = __expf(s[0][r] - nm);
            float p1 = __expf(s[1][r] - nm);
            s[0][r] = p0;
            s[1][r] = p1;
            float sum = p0 + p1;
            sum += __shfl_xor(sum, 1, 64);
            sum += __shfl_xor(sum, 2, 64);
            sum += __shfl_xor(sum, 4, 64);
            sum += __shfl_xor(sum, 8, 64);
            l_r[r] = l_r[r] * alpha[r] + sum;
        }
#pragma unroll
        for (int nt = 0; nt < 4; nt++)
#pragma unroll
            for (int r = 0; r < 4; r++) acc[nt][r] *= alpha[r];

        short* pt = (short*)Pt[wave];
#pragma unroll
        for (int sub = 0; sub < 2; sub++)
#pragma unroll
            for (int r = 0; r < 4; r++)
                pt[(lq * 4 + r) * VP + sub * 16 + lrow] = f2bf(s[sub][r]);

        short8 pf = *(short8*)(pt + lrow * VP + lq * 8);
#pragma unroll
        for (int nt = 0; nt < 4; nt++) {
            short8 vf = *(short8*)(&Vt[(nt * 16 + lrow) * VP + lq * 8]);
            acc[nt] = mfma16(pf, vf, acc[nt]);
        }
        __syncthreads();
    }

    float inv[4];
#pragma unroll
    for (int r = 0; r < 4; r++) inv[r] = 1.f / l_r[r];
    short* ob = AO + ((size_t)bh * S + q0 + wave * 16) * 64;
#pragma unroll
    for (int nt = 0; nt < 4; nt++)
#pragma unroll
        for (int r = 0; r < 4; r++)
            ob[(lq * 4 + r) * 64 + nt * 16 + lrow] = f2bf(scrub(acc[nt][r] * inv[r], 4e4f));
}

// ---- launch ----
// ws map: [0,64K) flag | [64K,128K) bq_bf | [128K,192K) bo_bf |
//         [1M,7M) WqkvT | [7M,9M) WoutT | [9M,25M) AO | [25M,..) QKV chunk
extern "C" void kernel_launch(void* const* d_in, const int* in_sizes, int n_in,
                              void* d_out, int out_size, void* d_ws, size_t ws_size,
                              hipStream_t stream) {
    char* ws = (char*)d_ws;
    int*   flag  = (int*)ws;
    short* bq_bf = (short*)(ws + 65536);
    short* bo_bf = (short*)(ws + 131072);
    short* WqkvT = (short*)(ws + (1ull << 20));
    short* WoutT = (short*)(ws + 7ull * (1ull << 20));
    short* AO    = (short*)(ws + 9ull * (1ull << 20));
    short* QKVc  = (short*)(ws + 25ull * (1ull << 20));

    int chunk_rows = 0;
    if      (ws_size >= 73ull * 1048576) chunk_rows = 8192;
    else if (ws_size >= 49ull * 1048576) chunk_rows = 4096;
    else if (ws_size >= 37ull * 1048576) chunk_rows = 2048;

    detect_dtype<<<1, 256, 0, stream>>>((const unsigned short*)d_in[0], flag);

    if (chunk_rows == 0) {
        fill_sentinel<<<(8388608 + 255) / 256, 256, 0, stream>>>(d_out, 8388608, flag);
        return;
    }

    conv_bias<<<12, 256, 0, stream>>>(d_in[2], bq_bf, 3072, flag);
    conv_bias<<<4, 256, 0, stream>>>(d_in[4], bo_bf, 1024, flag);
    transpose_poly<<<dim3(96, 32), 256, 0, stream>>>(d_in[1], WqkvT, 1024, 3072, flag);
    transpose_poly<<<dim3(32, 32), 256, 0, stream>>>(d_in[3], WoutT, 1024, 1024, flag);

    for (int r0 = 0; r0 < 8192; r0 += chunk_rows) {
        gemm_bt<<<dim3(24, chunk_rows / 128), 256, 0, stream>>>(
            d_in[0], WqkvT, bq_bf, QKVc, 3072, 1024, r0, flag, 1, 0, 8e4f);
        attn_kernel<<<dim3(32, (chunk_rows / 2048) * 16), 256, 0, stream>>>(
            QKVc, AO + (size_t)r0 * 1024, (const int*)d_in[5]);
    }

    gemm_bt<<<dim3(8, 64), 256, 0, stream>>>(
        AO, WoutT, bo_bf, d_out, 1024, 1024, 0, flag, 0, 1, 2e4f);
}

// Round 5
// 428.877 us; speedup vs baseline: 1.4949x; 1.4949x over previous
//
#include <hip/hip_runtime.h>
#include <hip/hip_bf16.h>

typedef __attribute__((ext_vector_type(8))) short short8;
typedef __attribute__((ext_vector_type(4))) float f32x4;

__device__ inline f32x4 mfma16(short8 a, short8 b, f32x4 c) {
    return __builtin_amdgcn_mfma_f32_16x16x32_bf16(a, b, c, 0, 0, 0);
}
__device__ inline short f2bf(float x) {
    __hip_bfloat16 h = __float2bfloat16(x);
    return *reinterpret_cast<short*>(&h);
}
__device__ inline unsigned short f2bfu(float x) {
    __hip_bfloat16 h = __float2bfloat16(x);
    return *reinterpret_cast<unsigned short*>(&h);
}
__device__ inline float scrub(float v, float s) {
    return (fabsf(v) < 1e30f) ? v : s;  // NaN/inf -> sentinel
}

// ---- dtype detection: flag=1 if x is fp32 (read-as-bf16 looks implausible) --
__global__ void detect_dtype(const unsigned short* __restrict__ x, int* flag) {
    __shared__ int cnt;
    if (threadIdx.x == 0) cnt = 0;
    __syncthreads();
    int c = 0;
    for (int i = threadIdx.x; i < 1024; i += 256) {
        unsigned short u = x[i];
        int e = (u >> 7) & 0xFF;
        if ((u & 0x7FFF) == 0 || (e >= 110 && e <= 143)) c++;
    }
    atomicAdd(&cnt, c);
    __syncthreads();
    if (threadIdx.x == 0) flag[0] = (cnt < 819) ? 1 : 0;
}

__global__ void conv_bias(const void* __restrict__ in, short* __restrict__ out,
                          int n, const int* __restrict__ flag) {
    int i = blockIdx.x * 256 + threadIdx.x;
    if (i >= n) return;
    out[i] = (*flag) ? f2bf(((const float*)in)[i]) : ((const short*)in)[i];
}

// ---- x (fp32 or bf16) -> bf16, 4 elems/thread ----
__global__ __launch_bounds__(256) void conv_x(const void* __restrict__ in,
                                              short* __restrict__ out, int n,
                                              const int* __restrict__ flag) {
    int i = (blockIdx.x * 256 + threadIdx.x) * 4;
    if (i >= n) return;
    if (*flag) {
        float4 f = *(const float4*)((const float*)in + i);
        unsigned int u0 = ((unsigned int)f2bfu(f.y) << 16) | f2bfu(f.x);
        unsigned int u1 = ((unsigned int)f2bfu(f.w) << 16) | f2bfu(f.z);
        *(uint2*)(out + i) = make_uint2(u0, u1);
    } else {
        *(uint2*)(out + i) = *(const uint2*)((const short*)in + i);
    }
}

__global__ void fill_sentinel(void* out, int n, const int* __restrict__ flag) {
    int i = blockIdx.x * 256 + threadIdx.x;
    if (i >= n) return;
    if (*flag) ((float*)out)[i] = 3e5f; else ((short*)out)[i] = f2bf(3e5f);
}

// ---- transpose (poly input): in[R][C] -> out[C][R], out bf16 ----
__global__ __launch_bounds__(256) void transpose_poly(const void* __restrict__ in,
                                                      short* __restrict__ out,
                                                      int R, int C,
                                                      const int* __restrict__ flag) {
    __shared__ short tile[32][33];
    const bool f32 = (*flag) != 0;
    int tx = threadIdx.x & 31, ty = threadIdx.x >> 5;
    int r0 = blockIdx.y * 32, c0 = blockIdx.x * 32;
#pragma unroll
    for (int i = 0; i < 4; i++) {
        size_t off = (size_t)(r0 + ty + i * 8) * C + c0 + tx;
        tile[ty + i * 8][tx] = f32 ? f2bf(((const float*)in)[off]) : ((const short*)in)[off];
    }
    __syncthreads();
#pragma unroll
    for (int i = 0; i < 4; i++)
        out[(size_t)(c0 + ty + i * 8) * R + r0 + tx] = tile[tx][ty + i * 8];
}

// ---- GEMM: C[M,N] = A[M,K] @ Bt[N,K]^T + bias; A bf16, C poly ----
#define LDK 72

__global__ __launch_bounds__(256) void gemm_bt(const short* __restrict__ A,
                                               const short* __restrict__ Bt,
                                               const short* __restrict__ bias,
                                               void* __restrict__ Cv,
                                               int N, int K,
                                               const int* __restrict__ flag,
                                               int c_poly, float sent) {
    alignas(16) __shared__ short As[128 * LDK];
    alignas(16) __shared__ short Bs[128 * LDK];
    const bool cf32 = c_poly && (*flag);
    int tid = threadIdx.x;
    int wave = tid >> 6, lane = tid & 63;
    int lrow = lane & 15, lq = lane >> 4;
    int wm = (wave >> 1) * 64, wn = (wave & 1) * 64;
    int m0 = blockIdx.y * 128, n0 = blockIdx.x * 128;

    f32x4 acc[4][4];
#pragma unroll
    for (int i = 0; i < 4; i++)
#pragma unroll
        for (int j = 0; j < 4; j++) acc[i][j] = (f32x4){0.f, 0.f, 0.f, 0.f};

    int srow = tid >> 3;
    int scol = (tid & 7) * 8;

    for (int kb = 0; kb < K; kb += 64) {
#pragma unroll
        for (int p = 0; p < 4; p++) {
            int row = p * 32 + srow;
            *(short8*)&As[row * LDK + scol] =
                *(const short8*)&A[(size_t)(m0 + row) * K + kb + scol];
            *(short8*)&Bs[row * LDK + scol] =
                *(const short8*)&Bt[(size_t)(n0 + row) * K + kb + scol];
        }
        __syncthreads();
#pragma unroll
        for (int ks = 0; ks < 2; ks++) {
            short8 af[4], bf[4];
#pragma unroll
            for (int i = 0; i < 4; i++)
                af[i] = *(short8*)&As[(wm + i * 16 + lrow) * LDK + ks * 32 + lq * 8];
#pragma unroll
            for (int i = 0; i < 4; i++)
                bf[i] = *(short8*)&Bs[(wn + i * 16 + lrow) * LDK + ks * 32 + lq * 8];
#pragma unroll
            for (int i = 0; i < 4; i++)
#pragma unroll
                for (int j = 0; j < 4; j++)
                    acc[i][j] = mfma16(af[i], bf[j], acc[i][j]);
        }
        __syncthreads();
    }

    const __hip_bfloat16* bias16 = (const __hip_bfloat16*)bias;
#pragma unroll
    for (int j = 0; j < 4; j++) {
        int col = n0 + wn + j * 16 + lrow;
        float bv = __bfloat162float(bias16[col]);
#pragma unroll
        for (int i = 0; i < 4; i++) {
            int rbase = m0 + wm + i * 16 + lq * 4;
#pragma unroll
            for (int r = 0; r < 4; r++) {
                float val = scrub(acc[i][j][r] + bv, sent);
                size_t off = (size_t)(rbase + r) * N + col;
                if (cf32) ((float*)Cv)[off] = val; else ((short*)Cv)[off] = f2bf(val);
            }
        }
    }
}

// ---- flash attention, S^T formulation -------------------------------------
// S^T = K·Q^T via mfma(kf, qf): lane owns ONE q (col=lane&15), 16 kv values
// (row = lq*4+r per 16-sub). Softmax per-lane + 2 shuffles. P^T B-operand
// built by register shuffles (no LDS round-trip). O^T = V^T·P^T accumulated
// in C-layout [d][q]. 64-kv tiles, double-buffered Vt, 1 barrier/iter.
// Block = 64 q rows (4 waves x 16 q); pairing: block i does q-tiles 64i and
// 1984-64i -> 33 iters each (causal balance).
#define VP2 72  // Vt pitch: 144B, 16B-aligned

__global__ __launch_bounds__(256) void attn_kernel(const short* __restrict__ QKV,
                                                   short* __restrict__ AO,
                                                   const int* __restrict__ maskp) {
    constexpr int S = 2048, C3 = 3072;
    alignas(16) __shared__ short Vt[2][64 * VP2];

    int tid = threadIdx.x;
    int wave = tid >> 6, lane = tid & 63;
    int lrow = lane & 15, lq = lane >> 4;
    int bh = blockIdx.y;
    const bool causal = (*maskp) != 0;
    const short* base = QKV + (size_t)(bh >> 4) * S * C3 + (bh & 15) * 192;

    int vi = tid & 63;            // kv row for V staging
    int vd0 = (tid >> 6) * 16;    // d base (16 d per thread)
    int LA = lrow + 32 * (lq & 1);
    int LB = LA + 16;
    const bool hi = (lq >> 1) != 0;

    int buf = 0;
    for (int tile = 0; tile < 2; tile++) {
        int q0t = (tile == 0) ? blockIdx.x * 64 : 1984 - blockIdx.x * 64;
        int qg = q0t + wave * 16 + lrow;     // this lane's q
        short8 qf0 = *(const short8*)(base + (size_t)qg * C3 + lq * 8);
        short8 qf1 = *(const short8*)(base + (size_t)qg * C3 + 32 + lq * 8);

        float m_i = -1e38f, l_i = 0.f;
        f32x4 acc[4];
#pragma unroll
        for (int nt = 0; nt < 4; nt++) acc[nt] = (f32x4){0.f, 0.f, 0.f, 0.f};

        int nkv = causal ? (q0t + 64) : S;

        for (int kv0 = 0; kv0 < nkv; kv0 += 64) {
            // stage V^T chunk (64 kv x 64 d) into Vt[buf]
            {
                const short* vsrc = base + (size_t)(kv0 + vi) * C3 + 128 + vd0;
                short8 va = *(const short8*)vsrc;
                short8 vb = *(const short8*)(vsrc + 8);
                short* vt = (short*)Vt[buf];
#pragma unroll
                for (int j = 0; j < 8; j++) vt[(vd0 + j) * VP2 + vi] = va[j];
#pragma unroll
                for (int j = 0; j < 8; j++) vt[(vd0 + 8 + j) * VP2 + vi] = vb[j];
            }
            __syncthreads();

            // S^T: 4 subtiles of 16 kv each
            f32x4 s[4];
#pragma unroll
            for (int sub = 0; sub < 4; sub++) {
                const short* kb = base + (size_t)(kv0 + sub * 16 + lrow) * C3 + 64;
                short8 kf0 = *(const short8*)(kb + lq * 8);
                short8 kf1 = *(const short8*)(kb + 32 + lq * 8);
                f32x4 a = (f32x4){0.f, 0.f, 0.f, 0.f};
                a = mfma16(kf0, qf0, a);
                a = mfma16(kf1, qf1, a);
                s[sub] = a;
            }

            // causal mask: kv = kv0+sub*16+lq*4+r, q = qg (only diagonal chunk)
            if (causal && (kv0 + 63 > q0t + wave * 16)) {
#pragma unroll
                for (int sub = 0; sub < 4; sub++) {
                    int kvg = kv0 + sub * 16 + lq * 4;
#pragma unroll
                    for (int r = 0; r < 4; r++)
                        if (kvg + r > qg) s[sub][r] = -1e30f;
                }
            }

            // online softmax on raw scores, scale 1/8 folded into exp
            float vmax = -1e38f;
#pragma unroll
            for (int sub = 0; sub < 4; sub++) {
                float a = fmaxf(fmaxf(s[sub][0], s[sub][1]), fmaxf(s[sub][2], s[sub][3]));
                vmax = fmaxf(vmax, a);
            }
            vmax = fmaxf(vmax, __shfl_xor(vmax, 16, 64));
            vmax = fmaxf(vmax, __shfl_xor(vmax, 32, 64));
            float mnew = fmaxf(m_i, vmax);
            float alpha = __expf(0.125f * (m_i - mnew));
            float c = -0.125f * mnew;
            float lsum = 0.f;
#pragma unroll
            for (int sub = 0; sub < 4; sub++) {
#pragma unroll
                for (int r = 0; r < 4; r++) {
                    float p = __expf(fmaf(s[sub][r], 0.125f, c));
                    s[sub][r] = p;
                    lsum += p;
                }
            }
            lsum += __shfl_xor(lsum, 16, 64);
            lsum += __shfl_xor(lsum, 32, 64);
            l_i = l_i * alpha + lsum;
            m_i = mnew;
#pragma unroll
            for (int nt = 0; nt < 4; nt++)
#pragma unroll
                for (int r = 0; r < 4; r++) acc[nt][r] *= alpha;

            // pack P (bf16x2): pk[sub][h] = (s[sub][2h+1], s[sub][2h])
            unsigned int pk[4][2];
#pragma unroll
            for (int sub = 0; sub < 4; sub++) {
                pk[sub][0] = ((unsigned int)f2bfu(s[sub][1]) << 16) | f2bfu(s[sub][0]);
                pk[sub][1] = ((unsigned int)f2bfu(s[sub][3]) << 16) | f2bfu(s[sub][2]);
            }

            // PV: O^T += V^T · P^T, P^T frag gathered via shuffles
            short* vt = (short*)Vt[buf];
#pragma unroll
            for (int ks = 0; ks < 2; ks++) {
                unsigned int f0a = __shfl((int)pk[2 * ks][0], LA, 64);
                unsigned int f1a = __shfl((int)pk[2 * ks + 1][0], LA, 64);
                unsigned int g0a = __shfl((int)pk[2 * ks][1], LA, 64);
                unsigned int g1a = __shfl((int)pk[2 * ks + 1][1], LA, 64);
                unsigned int f0b = __shfl((int)pk[2 * ks][0], LB, 64);
                unsigned int f1b = __shfl((int)pk[2 * ks + 1][0], LB, 64);
                unsigned int g0b = __shfl((int)pk[2 * ks][1], LB, 64);
                unsigned int g1b = __shfl((int)pk[2 * ks + 1][1], LB, 64);
                union { unsigned int u[4]; short8 v; } pf;
                pf.u[0] = hi ? f1a : f0a;
                pf.u[1] = hi ? g1a : g0a;
                pf.u[2] = hi ? f1b : f0b;
                pf.u[3] = hi ? g1b : g0b;
#pragma unroll
                for (int nt = 0; nt < 4; nt++) {
                    short8 vf = *(short8*)&vt[(nt * 16 + lrow) * VP2 + ks * 32 + lq * 8];
                    acc[nt] = mfma16(vf, pf.v, acc[nt]);
                }
            }
            buf ^= 1;
        }

        // epilogue: O^T[d][q] -> AO[q][d], packed 8B stores
        float inv = 1.f / l_i;
        short* ob = AO + ((size_t)bh * S + qg) * 64;
#pragma unroll
        for (int nt = 0; nt < 4; nt++) {
            unsigned int u0 = ((unsigned int)f2bfu(scrub(acc[nt][1] * inv, 4e4f)) << 16) |
                              f2bfu(scrub(acc[nt][0] * inv, 4e4f));
            unsigned int u1 = ((unsigned int)f2bfu(scrub(acc[nt][3] * inv, 4e4f)) << 16) |
                              f2bfu(scrub(acc[nt][2] * inv, 4e4f));
            *(uint2*)(ob + nt * 16 + lq * 4) = make_uint2(u0, u1);
        }
    }
}

// ---- launch ----
// ws map: [0,64K) flag | [64K,128K) bq_bf | [128K,192K) bo_bf |
//         [1M,7M) WqkvT | [7M,9M) WoutT | [9M,25M) x_bf then AO | [25M,73M) QKV
extern "C" void kernel_launch(void* const* d_in, const int* in_sizes, int n_in,
                              void* d_out, int out_size, void* d_ws, size_t ws_size,
                              hipStream_t stream) {
    char* ws = (char*)d_ws;
    int*   flag  = (int*)ws;
    short* bq_bf = (short*)(ws + 65536);
    short* bo_bf = (short*)(ws + 131072);
    short* WqkvT = (short*)(ws + (1ull << 20));
    short* WoutT = (short*)(ws + 7ull * (1ull << 20));
    short* xbfAO = (short*)(ws + 9ull * (1ull << 20));   // x_bf, later AO
    short* QKVc  = (short*)(ws + 25ull * (1ull << 20));

    detect_dtype<<<1, 256, 0, stream>>>((const unsigned short*)d_in[0], flag);

    if (ws_size < 73ull * 1048576) {
        fill_sentinel<<<(8388608 + 255) / 256, 256, 0, stream>>>(d_out, 8388608, flag);
        return;
    }

    conv_bias<<<12, 256, 0, stream>>>(d_in[2], bq_bf, 3072, flag);
    conv_bias<<<4, 256, 0, stream>>>(d_in[4], bo_bf, 1024, flag);
    transpose_poly<<<dim3(96, 32), 256, 0, stream>>>(d_in[1], WqkvT, 1024, 3072, flag);
    transpose_poly<<<dim3(32, 32), 256, 0, stream>>>(d_in[3], WoutT, 1024, 1024, flag);
    conv_x<<<8192, 256, 0, stream>>>(d_in[0], xbfAO, 8388608, flag);

    gemm_bt<<<dim3(24, 64), 256, 0, stream>>>(xbfAO, WqkvT, bq_bf, QKVc,
                                              3072, 1024, flag, 0, 8e4f);
    attn_kernel<<<dim3(16, 64), 256, 0, stream>>>(QKVc, xbfAO, (const int*)d_in[5]);
    gemm_bt<<<dim3(8, 64), 256, 0, stream>>>(xbfAO, WoutT, bo_bf, d_out,
                                             1024, 1024, flag, 1, 2e4f);
}

// Round 7
// 330.568 us; speedup vs baseline: 1.9394x; 1.2974x over previous
//
#include <hip/hip_runtime.h>
#include <hip/hip_bf16.h>

typedef __attribute__((ext_vector_type(8))) short short8;
typedef __attribute__((ext_vector_type(4))) float f32x4;

__device__ inline f32x4 mfma16(short8 a, short8 b, f32x4 c) {
    return __builtin_amdgcn_mfma_f32_16x16x32_bf16(a, b, c, 0, 0, 0);
}
__device__ inline short f2bf(float x) {
    __hip_bfloat16 h = __float2bfloat16(x);
    return *reinterpret_cast<short*>(&h);
}
__device__ inline unsigned short f2bfu(float x) {
    __hip_bfloat16 h = __float2bfloat16(x);
    return *reinterpret_cast<unsigned short*>(&h);
}
__device__ inline float bf2f(short u) {
    __hip_bfloat16 h = *reinterpret_cast<__hip_bfloat16*>(&u);
    return __bfloat162float(h);
}
__device__ inline float scrub(float v, float s) {
    return (fabsf(v) < 1e30f) ? v : s;
}
__device__ inline short8 scaleq(short8 v) {   // fold 1/sqrt(hd)=0.125 into Q
    short8 r;
#pragma unroll
    for (int j = 0; j < 8; j++) r[j] = f2bf(bf2f(v[j]) * 0.125f);
    return r;
}

// ---- dtype detection ----
__global__ void detect_dtype(const unsigned short* __restrict__ x, int* flag) {
    __shared__ int cnt;
    if (threadIdx.x == 0) cnt = 0;
    __syncthreads();
    int c = 0;
    for (int i = threadIdx.x; i < 1024; i += 256) {
        unsigned short u = x[i];
        int e = (u >> 7) & 0xFF;
        if ((u & 0x7FFF) == 0 || (e >= 110 && e <= 143)) c++;
    }
    atomicAdd(&cnt, c);
    __syncthreads();
    if (threadIdx.x == 0) flag[0] = (cnt < 819) ? 1 : 0;
}

__global__ void conv_bias(const void* __restrict__ in, short* __restrict__ out,
                          int n, const int* __restrict__ flag) {
    int i = blockIdx.x * 256 + threadIdx.x;
    if (i >= n) return;
    out[i] = (*flag) ? f2bf(((const float*)in)[i]) : ((const short*)in)[i];
}

__global__ __launch_bounds__(256) void conv_x(const void* __restrict__ in,
                                              short* __restrict__ out, int n,
                                              const int* __restrict__ flag) {
    int i = (blockIdx.x * 256 + threadIdx.x) * 4;
    if (i >= n) return;
    if (*flag) {
        float4 f = *(const float4*)((const float*)in + i);
        unsigned int u0 = ((unsigned int)f2bfu(f.y) << 16) | f2bfu(f.x);
        unsigned int u1 = ((unsigned int)f2bfu(f.w) << 16) | f2bfu(f.z);
        *(uint2*)(out + i) = make_uint2(u0, u1);
    } else {
        *(uint2*)(out + i) = *(const uint2*)((const short*)in + i);
    }
}

__global__ void fill_sentinel(void* out, int n, const int* __restrict__ flag) {
    int i = blockIdx.x * 256 + threadIdx.x;
    if (i >= n) return;
    if (*flag) ((float*)out)[i] = 3e5f; else ((short*)out)[i] = f2bf(3e5f);
}

// ---- transpose (poly input) ----
__global__ __launch_bounds__(256) void transpose_poly(const void* __restrict__ in,
                                                      short* __restrict__ out,
                                                      int R, int C,
                                                      const int* __restrict__ flag) {
    __shared__ short tile[32][33];
    const bool f32 = (*flag) != 0;
    int tx = threadIdx.x & 31, ty = threadIdx.x >> 5;
    int r0 = blockIdx.y * 32, c0 = blockIdx.x * 32;
#pragma unroll
    for (int i = 0; i < 4; i++) {
        size_t off = (size_t)(r0 + ty + i * 8) * C + c0 + tx;
        tile[ty + i * 8][tx] = f32 ? f2bf(((const float*)in)[off]) : ((const short*)in)[off];
    }
    __syncthreads();
#pragma unroll
    for (int i = 0; i < 4; i++)
        out[(size_t)(c0 + ty + i * 8) * R + r0 + tx] = tile[tx][ty + i * 8];
}

// ---- GEMM (unchanged) ----
#define LDK 72

__global__ __launch_bounds__(256) void gemm_bt(const short* __restrict__ A,
                                               const short* __restrict__ Bt,
                                               const short* __restrict__ bias,
                                               void* __restrict__ Cv,
                                               int N, int K,
                                               const int* __restrict__ flag,
                                               int c_poly, float sent) {
    alignas(16) __shared__ short As[128 * LDK];
    alignas(16) __shared__ short Bs[128 * LDK];
    const bool cf32 = c_poly && (*flag);
    int tid = threadIdx.x;
    int wave = tid >> 6, lane = tid & 63;
    int lrow = lane & 15, lq = lane >> 4;
    int wm = (wave >> 1) * 64, wn = (wave & 1) * 64;
    int m0 = blockIdx.y * 128, n0 = blockIdx.x * 128;

    f32x4 acc[4][4];
#pragma unroll
    for (int i = 0; i < 4; i++)
#pragma unroll
        for (int j = 0; j < 4; j++) acc[i][j] = (f32x4){0.f, 0.f, 0.f, 0.f};

    int srow = tid >> 3;
    int scol = (tid & 7) * 8;

    for (int kb = 0; kb < K; kb += 64) {
#pragma unroll
        for (int p = 0; p < 4; p++) {
            int row = p * 32 + srow;
            *(short8*)&As[row * LDK + scol] =
                *(const short8*)&A[(size_t)(m0 + row) * K + kb + scol];
            *(short8*)&Bs[row * LDK + scol] =
                *(const short8*)&Bt[(size_t)(n0 + row) * K + kb + scol];
        }
        __syncthreads();
#pragma unroll
        for (int ks = 0; ks < 2; ks++) {
            short8 af[4], bf[4];
#pragma unroll
            for (int i = 0; i < 4; i++)
                af[i] = *(short8*)&As[(wm + i * 16 + lrow) * LDK + ks * 32 + lq * 8];
#pragma unroll
            for (int i = 0; i < 4; i++)
                bf[i] = *(short8*)&Bs[(wn + i * 16 + lrow) * LDK + ks * 32 + lq * 8];
#pragma unroll
            for (int i = 0; i < 4; i++)
#pragma unroll
                for (int j = 0; j < 4; j++)
                    acc[i][j] = mfma16(af[i], bf[j], acc[i][j]);
        }
        __syncthreads();
    }

    const __hip_bfloat16* bias16 = (const __hip_bfloat16*)bias;
#pragma unroll
    for (int j = 0; j < 4; j++) {
        int col = n0 + wn + j * 16 + lrow;
        float bv = __bfloat162float(bias16[col]);
#pragma unroll
        for (int i = 0; i < 4; i++) {
            int rbase = m0 + wm + i * 16 + lq * 4;
#pragma unroll
            for (int r = 0; r < 4; r++) {
                float val = scrub(acc[i][j][r] + bv, sent);
                size_t off = (size_t)(rbase + r) * N + col;
                if (cf32) ((float*)Cv)[off] = val; else ((short*)Cv)[off] = f2bf(val);
            }
        }
    }
}

// ---- flash attention, S^T formulation, 128 q / block ----------------------
// Block = 128 q (4 waves x 2 groups x 16 q), processes tile pair
// (128*bx, 1920-128*bx) sequentially -> 34 group-iters causal-balanced.
// Per 64-kv iter: shared V^T stage (8 ds_write_b32/thread) + shared K loads +
// shared vf reads; per group: softmax, P -> wave-private LDS (4 ds_write_b64),
// B-frag = ds_read_b128. No shuffle-based P gather.
#define VP2 72
#define PP 72

__global__ __launch_bounds__(256) void attn_kernel(const short* __restrict__ QKV,
                                                   short* __restrict__ AO,
                                                   const int* __restrict__ maskp) {
    constexpr int S = 2048, C3 = 3072;
    alignas(16) __shared__ short Vt[2][64 * VP2];
    alignas(16) __shared__ short Pt[4][2][16 * PP];

    int tid = threadIdx.x;
    int wave = tid >> 6, lane = tid & 63;
    int lrow = lane & 15, lq = lane >> 4;
    int bh = blockIdx.y;
    const bool causal = (*maskp) != 0;
    const short* base = QKV + (size_t)(bh >> 4) * S * C3 + (bh & 15) * 192;

    int vi2 = (tid & 31) * 2;     // kv pair base for V staging
    int vd0 = (tid >> 5) * 8;     // 8 d per thread

    int buf = 0;
    for (int tile = 0; tile < 2; tile++) {
        int q0t = (tile == 0) ? blockIdx.x * 128 : 1920 - blockIdx.x * 128;

        int qg[2];
        short8 qf0[2], qf1[2];
#pragma unroll
        for (int g = 0; g < 2; g++) {
            qg[g] = q0t + wave * 32 + g * 16 + lrow;
            qf0[g] = scaleq(*(const short8*)(base + (size_t)qg[g] * C3 + lq * 8));
            qf1[g] = scaleq(*(const short8*)(base + (size_t)qg[g] * C3 + 32 + lq * 8));
        }

        float m_i[2] = {-1e38f, -1e38f}, l_i[2] = {0.f, 0.f};
        f32x4 acc[2][4];
#pragma unroll
        for (int g = 0; g < 2; g++)
#pragma unroll
            for (int nt = 0; nt < 4; nt++) acc[g][nt] = (f32x4){0.f, 0.f, 0.f, 0.f};

        int nkv = causal ? (q0t + 128) : S;

        for (int kv0 = 0; kv0 < nkv; kv0 += 64) {
            // ---- stage V^T (64 kv x 64 d): 2 kv x 8 d per thread ----
            {
                const short* vs0 = base + (size_t)(kv0 + vi2) * C3 + 128 + vd0;
                union { short8 v; unsigned short u[8]; } a, b;
                a.v = *(const short8*)vs0;
                b.v = *(const short8*)(vs0 + C3);
                unsigned int* vt = (unsigned int*)&Vt[buf][0];
#pragma unroll
                for (int j = 0; j < 8; j++)
                    vt[((vd0 + j) * VP2 + vi2) >> 1] =
                        ((unsigned int)b.u[j] << 16) | a.u[j];
            }
            __syncthreads();

            // ---- S^T for both groups, shared K loads ----
            f32x4 s[2][4];
#pragma unroll
            for (int sub = 0; sub < 4; sub++) {
                const short* kb = base + (size_t)(kv0 + sub * 16 + lrow) * C3 + 64;
                short8 kf0 = *(const short8*)(kb + lq * 8);
                short8 kf1 = *(const short8*)(kb + 32 + lq * 8);
#pragma unroll
                for (int g = 0; g < 2; g++) {
                    f32x4 a = (f32x4){0.f, 0.f, 0.f, 0.f};
                    a = mfma16(kf0, qf0[g], a);
                    a = mfma16(kf1, qf1[g], a);
                    s[g][sub] = a;
                }
            }

            // ---- per-group: mask, online softmax, pack P to LDS ----
#pragma unroll
            for (int g = 0; g < 2; g++) {
                if (causal && (kv0 + 63 > q0t + wave * 32 + g * 16)) {
#pragma unroll
                    for (int sub = 0; sub < 4; sub++) {
                        int kvg = kv0 + sub * 16 + lq * 4;
#pragma unroll
                        for (int r = 0; r < 4; r++)
                            if (kvg + r > qg[g]) s[g][sub][r] = -1e30f;
                    }
                }
                float vmax = -1e38f;
#pragma unroll
                for (int sub = 0; sub < 4; sub++) {
                    float a = fmaxf(fmaxf(s[g][sub][0], s[g][sub][1]),
                                    fmaxf(s[g][sub][2], s[g][sub][3]));
                    vmax = fmaxf(vmax, a);
                }
                vmax = fmaxf(vmax, __shfl_xor(vmax, 16, 64));
                vmax = fmaxf(vmax, __shfl_xor(vmax, 32, 64));
                float mnew = fmaxf(m_i[g], vmax);
                float alpha = __expf(m_i[g] - mnew);
                float lsum = 0.f;
                unsigned int pk[4][2];
#pragma unroll
                for (int sub = 0; sub < 4; sub++) {
                    float p0 = __expf(s[g][sub][0] - mnew);
                    float p1 = __expf(s[g][sub][1] - mnew);
                    float p2 = __expf(s[g][sub][2] - mnew);
                    float p3 = __expf(s[g][sub][3] - mnew);
                    lsum += (p0 + p1) + (p2 + p3);
                    pk[sub][0] = ((unsigned int)f2bfu(p1) << 16) | f2bfu(p0);
                    pk[sub][1] = ((unsigned int)f2bfu(p3) << 16) | f2bfu(p2);
                }
                lsum += __shfl_xor(lsum, 16, 64);
                lsum += __shfl_xor(lsum, 32, 64);
                l_i[g] = l_i[g] * alpha + lsum;
                m_i[g] = mnew;
#pragma unroll
                for (int nt = 0; nt < 4; nt++)
#pragma unroll
                    for (int r = 0; r < 4; r++) acc[g][nt][r] *= alpha;
                // P[q=lrow][kv=sub*16+lq*4 .. +3] : 4 x ds_write_b64
                unsigned int* pt = (unsigned int*)&Pt[wave][g][0];
#pragma unroll
                for (int sub = 0; sub < 4; sub++)
                    *(uint2*)&pt[(lrow * PP + sub * 16 + lq * 4) >> 1] =
                        make_uint2(pk[sub][0], pk[sub][1]);
            }

            // ---- PV: O^T += V^T · P^T, vf shared across groups ----
#pragma unroll
            for (int ks = 0; ks < 2; ks++) {
                short8 pfA = *(short8*)&Pt[wave][0][lrow * PP + ks * 32 + lq * 8];
                short8 pfB = *(short8*)&Pt[wave][1][lrow * PP + ks * 32 + lq * 8];
#pragma unroll
                for (int nt = 0; nt < 4; nt++) {
                    short8 vf = *(short8*)&Vt[buf][(nt * 16 + lrow) * VP2 + ks * 32 + lq * 8];
                    acc[0][nt] = mfma16(vf, pfA, acc[0][nt]);
                    acc[1][nt] = mfma16(vf, pfB, acc[1][nt]);
                }
            }
            buf ^= 1;
        }

        // ---- epilogue ----
#pragma unroll
        for (int g = 0; g < 2; g++) {
            float inv = 1.f / l_i[g];
            short* ob = AO + ((size_t)bh * S + qg[g]) * 64;
#pragma unroll
            for (int nt = 0; nt < 4; nt++) {
                unsigned int u0 = ((unsigned int)f2bfu(scrub(acc[g][nt][1] * inv, 4e4f)) << 16) |
                                  f2bfu(scrub(acc[g][nt][0] * inv, 4e4f));
                unsigned int u1 = ((unsigned int)f2bfu(scrub(acc[g][nt][3] * inv, 4e4f)) << 16) |
                                  f2bfu(scrub(acc[g][nt][2] * inv, 4e4f));
                *(uint2*)(ob + nt * 16 + lq * 4) = make_uint2(u0, u1);
            }
        }
    }
}

// ---- launch ----
extern "C" void kernel_launch(void* const* d_in, const int* in_sizes, int n_in,
                              void* d_out, int out_size, void* d_ws, size_t ws_size,
                              hipStream_t stream) {
    char* ws = (char*)d_ws;
    int*   flag  = (int*)ws;
    short* bq_bf = (short*)(ws + 65536);
    short* bo_bf = (short*)(ws + 131072);
    short* WqkvT = (short*)(ws + (1ull << 20));
    short* WoutT = (short*)(ws + 7ull * (1ull << 20));
    short* xbfAO = (short*)(ws + 9ull * (1ull << 20));   // x_bf, later AO
    short* QKVc  = (short*)(ws + 25ull * (1ull << 20));

    detect_dtype<<<1, 256, 0, stream>>>((const unsigned short*)d_in[0], flag);

    if (ws_size < 73ull * 1048576) {
        fill_sentinel<<<(8388608 + 255) / 256, 256, 0, stream>>>(d_out, 8388608, flag);
        return;
    }

    conv_bias<<<12, 256, 0, stream>>>(d_in[2], bq_bf, 3072, flag);
    conv_bias<<<4, 256, 0, stream>>>(d_in[4], bo_bf, 1024, flag);
    transpose_poly<<<dim3(96, 32), 256, 0, stream>>>(d_in[1], WqkvT, 1024, 3072, flag);
    transpose_poly<<<dim3(32, 32), 256, 0, stream>>>(d_in[3], WoutT, 1024, 1024, flag);
    conv_x<<<8192, 256, 0, stream>>>(d_in[0], xbfAO, 8388608, flag);

    gemm_bt<<<dim3(24, 64), 256, 0, stream>>>(xbfAO, WqkvT, bq_bf, QKVc,
                                              3072, 1024, flag, 0, 8e4f);
    attn_kernel<<<dim3(8, 64), 256, 0, stream>>>(QKVc, xbfAO, (const int*)d_in[5]);
    gemm_bt<<<dim3(8, 64), 256, 0, stream>>>(xbfAO, WoutT, bo_bf, d_out,
                                             1024, 1024, flag, 1, 2e4f);
}